// Round 5
// baseline (424.190 us; speedup 1.0000x reference)
//
#include <hip/hip_runtime.h>
#include <math.h>

#define NB 16
#define NC 48
#define NT 96
#define NP 12
#define NFF 64
#define CT 4608          // NC*NT
#define STEPS 7
#define NBLK 1152        // 6 edge-blocks per (b,p) x 192 pairs
#define NTHR 192
#define NGRP 32          // barrier tree: 32 groups x 36 blocks
#define GSZ  36
// Co-residency: __launch_bounds__(192,4) -> 4 waves/EU -> 16 waves/CU ->
// 5 blocks/CU (15 waves). 5*256 = 1280 >= 1152 -> whole grid resident.
// LDS ~5 KB/block (cap at 5/CU is 32 KB), VGPR cap 512/4 = 128.

// ---- exact-GELU via Abramowitz-Stegun 7.1.26 erf (|abs err| <= 1.5e-7) ----
__device__ __forceinline__ float erf_fast(float x) {
    float a = fabsf(x);
    float t = __builtin_amdgcn_rcpf(fmaf(0.3275911f, a, 1.0f));
    float p = t * fmaf(t, fmaf(t, fmaf(t, fmaf(t, 1.061405429f, -1.453152027f),
                                       1.421413741f), -0.284496736f), 0.254829592f);
    float E = __builtin_amdgcn_exp2f(-a * a * 1.4426950408889634f);
    float y = fmaf(-p, E, 1.0f);
    return copysignf(y, x);
}
__device__ __forceinline__ float gelu_exact(float u) {
    float e  = erf_fast(u * 0.70710678118654752f);
    float hu = 0.5f * u;
    return fmaf(hu, e, hu);
}

// ---- LLC-coherent (cross-XCD) data path: sc0 sc1 bypasses the non-coherent
// per-XCD L2 -> no cache-maintenance fences needed anywhere. -----------------
__device__ __forceinline__ float load_f_llc(const float* p) {
    float v;
    asm volatile("global_load_dword %0, %1, off sc0 sc1" : "=v"(v) : "v"(p));
    return v;
}
__device__ __forceinline__ void store_f_llc(float* p, float v) {
    asm volatile("global_store_dword %0, %1, off sc0 sc1" :: "v"(p), "v"(v) : "memory");
}
__device__ __forceinline__ void waitcnt0() {
    asm volatile("s_waitcnt vmcnt(0)" ::: "memory");
}

// ---- two-level tree grid barrier, relaxed agent atomics only --------------
// bar[0..31] group counters, bar[32] global counter, bar[33] generation.
// Every __syncthreads() at entry drains each thread's vmem (compiler emits
// s_waitcnt vmcnt(0) before s_barrier), so all sc1 data stores are at the LLC
// before thread 0 arrives. Same-line TCC serialization orders the
// reset->add->gen chain (explicit waitcnt0 between dependent RMWs).
__device__ __forceinline__ void grid_barrier(unsigned* bar) {
    __syncthreads();
    if (threadIdx.x == 0) {
        waitcnt0();
        unsigned g = __hip_atomic_load(bar + 33, __ATOMIC_RELAXED, __HIP_MEMORY_SCOPE_AGENT);
        unsigned grp = blockIdx.x / GSZ;
        unsigned o = __hip_atomic_fetch_add(bar + grp, 1u, __ATOMIC_RELAXED, __HIP_MEMORY_SCOPE_AGENT);
        if (o == GSZ - 1u) {                       // last of my group
            __hip_atomic_store(bar + grp, 0u, __ATOMIC_RELAXED, __HIP_MEMORY_SCOPE_AGENT);
            waitcnt0();
            unsigned go = __hip_atomic_fetch_add(bar + 32, 1u, __ATOMIC_RELAXED, __HIP_MEMORY_SCOPE_AGENT);
            if (go == NGRP - 1u) {                 // last group overall
                __hip_atomic_store(bar + 32, 0u, __ATOMIC_RELAXED, __HIP_MEMORY_SCOPE_AGENT);
                waitcnt0();
                __hip_atomic_fetch_add(bar + 33, 1u, __ATOMIC_RELAXED, __HIP_MEMORY_SCOPE_AGENT);
            } else {
                while (__hip_atomic_load(bar + 33, __ATOMIC_RELAXED, __HIP_MEMORY_SCOPE_AGENT) == g)
                    __builtin_amdgcn_s_sleep(2);
            }
        } else {
            while (__hip_atomic_load(bar + 33, __ATOMIC_RELAXED, __HIP_MEMORY_SCOPE_AGENT) == g)
                __builtin_amdgcn_s_sleep(2);
        }
    }
    __syncthreads();
}

__global__ __launch_bounds__(NTHR, 4) void fused_kernel(
    const float* __restrict__ x,
    const float* __restrict__ g0, const float* __restrict__ b0,
    const float* __restrict__ g1, const float* __restrict__ b1,
    const float* __restrict__ g2, const float* __restrict__ b2,
    const float* __restrict__ Wagg, const float* __restrict__ bagg,
    const float* __restrict__ W1, const float* __restrict__ bm1,
    const float* __restrict__ W2, const float* __restrict__ wmsg,
    const float* __restrict__ bmsg,
    float* __restrict__ out, float* __restrict__ xn,
    float* __restrict__ t_ws, float* __restrict__ res_ws,
    unsigned* __restrict__ bar)
{
    const int blk = blockIdx.x, tid = threadIdx.x;

    __shared__ float4 coef[NFF];          // W1[f][0], W1[f][1], bm1[f], W2[f]
    __shared__ float tv[NC];
    __shared__ float erow[8][49];         // 8 rows per edge block, +1 pad
    __shared__ float rowm1[8], rowm3[8];
    __shared__ float red[8][2];
    __shared__ float sh[NTHR], shB[NTHR], wagg[144];

    if (tid < NFF)
        coef[tid] = make_float4(W1[2 * tid], W1[2 * tid + 1], bm1[tid], W2[tid]);

    // ---------------- bn0 (blocks 0..23): BN over full x -------------------
    if (blk < CT / NTHR) {
        int f = blk * NTHR + tid;
        float v[NB];
        float s = 0.f;
#pragma unroll
        for (int bb = 0; bb < NB; bb++) { v[bb] = x[bb * CT + f]; s += v[bb]; }
        float mu = s * (1.f / NB);
        float var = 0.f;
#pragma unroll
        for (int bb = 0; bb < NB; bb++) { float d = v[bb] - mu; var = fmaf(d, d, var); }
        var *= (1.f / NB);
        float rs = rsqrtf(var + 1e-5f);
        float g = g0[f], bbv = b0[f];
        int c = f / NT, tt = f % NT;
#pragma unroll
        for (int bb = 0; bb < NB; bb++) {
            float y = (v[bb] - mu) * rs * g + bbv;
            store_f_llc(&xn[bb * CT + f], y);
            if (tt < NP) store_f_llc(&out[(bb * NC + c) * NT + tt], y);
        }
    }
    grid_barrier(bar);

    const float wm = wmsg[0], bmv = bmsg[0];

    // edge-block geometry (fixed across steps)
    const int bp = blk / 6;                 // (b,p) pair, 0..191
    const int i0 = (blk % 6) * 8;           // this block's 8 output rows
    const int eb = bp / NP, ep = bp % NP;

    for (int s = 0; s < STEPS; s++) {
        // ---- phase1 (blocks 0..47, one per channel c): proven round-1 code
        if (blk < NC) {
            int c = blk;
            int b = tid / NP, p = tid % NP;
            if (tid < 144) wagg[tid] = Wagg[tid];
            float v = load_f_llc(&out[(b * NC + c) * NT + NP * s + p]);
            waitcnt0();
            sh[tid] = v;
            __syncthreads();
            float s1 = 0.f;
#pragma unroll
            for (int b2 = 0; b2 < NB; b2++) s1 += sh[b2 * NP + p];
            float mu = s1 * (1.f / NB);
            float var = 0.f;
#pragma unroll
            for (int b2 = 0; b2 < NB; b2++) { float d = sh[b2 * NP + p] - mu; var = fmaf(d, d, var); }
            var *= (1.f / NB);
            float inp = (v - mu) * rsqrtf(var + 1e-5f) * g1[c * NP + p] + b1[c * NP + p];
            shB[tid] = inp;
            __syncthreads();
            float acc = bagg[p];
#pragma unroll
            for (int pp = 0; pp < NP; pp++) acc = fmaf(shB[b * NP + pp], wagg[p * NP + pp], acc);
            float res = gelu_exact(acc) + xn[(b * NC + c) * NT + NP + NP * s + p];
            store_f_llc(&res_ws[(b * NC + c) * NP + p], res);
            sh[tid] = res;
            __syncthreads();
            float s2 = 0.f;
#pragma unroll
            for (int b2 = 0; b2 < NB; b2++) s2 += sh[b2 * NP + p];
            float mu2 = s2 * (1.f / NB);
            float var2 = 0.f;
#pragma unroll
            for (int b2 = 0; b2 < NB; b2++) { float d = sh[b2 * NP + p] - mu2; var2 = fmaf(d, d, var2); }
            var2 *= (1.f / NB);
            float t = (res - mu2) * rsqrtf(var2 + 1e-5f) * g2[c * NP + p] + b2[c * NP + p];
            store_f_llc(&t_ws[(b * NP + p) * NC + c], t);
        }
        grid_barrier(bar);

        // ---- edge phase (all 1152 blocks): 8 rows, ILP=2 ------------------
        {
            float tvl = 0.f, resl = 0.f;
            if (tid < NC) tvl = load_f_llc(&t_ws[bp * NC + tid]);
            if (tid < 8)  resl = load_f_llc(&res_ws[(eb * NC + i0 + tid) * NP + ep]);
            waitcnt0();
            if (tid < NC) tv[tid] = tvl;
            if (tid < 16) ((float*)red)[tid] = 0.f;
            __syncthreads();

            int j = tid % NC, rg = tid / NC;      // rg in 0..3; rows rg, rg+4
            float zj = tv[j];
            float zi[2], e[2];
            zi[0] = tv[i0 + rg];     zi[1] = tv[i0 + rg + 4];
            e[0] = 0.f;              e[1] = 0.f;

#pragma unroll 8
            for (int f = 0; f < NFF; f++) {
                float4 cf = coef[f];
                float base = fmaf(cf.y, zj, cf.z);
                float u0 = fmaf(cf.x, zi[0], base);
                float u1 = fmaf(cf.x, zi[1], base);
                e[0] = fmaf(gelu_exact(u0), cf.w, e[0]);
                e[1] = fmaf(gelu_exact(u1), cf.w, e[1]);
            }
            erow[rg][j] = e[0];
            erow[rg + 4][j] = e[1];
            __syncthreads();

            if (tid < 8) {
                float m1 = -1e30f, m2 = -1e30f, m3 = -1e30f;
#pragma unroll 8
                for (int k = 0; k < NC; k++) {
                    float v = erow[tid][k];
                    float n1 = fmaxf(m1, v), r1 = fminf(m1, v);
                    float n2 = fmaxf(m2, r1), r2 = fminf(m2, r1);
                    float n3 = fmaxf(m3, r2);
                    m1 = n1; m2 = n2; m3 = n3;
                }
                rowm1[tid] = m1; rowm3[tid] = m3;
            }
            __syncthreads();

            float msg = fmaf(zj, wm, bmv);
#pragma unroll
            for (int k = 0; k < 2; k++) {
                int r = rg + 4 * k;
                float ek = e[k];
                if (ek >= rowm3[r]) {             // ~3 lanes per row
                    int rank = 0;
                    for (int kk = 0; kk < NC; kk++) {
                        float v = erow[r][kk];
                        rank += (v > ek) || (v == ek && kk < j);
                    }
                    if (rank < 3) {               // exact jax top_k tie-break
                        float w = __builtin_amdgcn_exp2f((ek - rowm1[r]) * 1.4426950408889634f);
                        atomicAdd(&red[r][0], w);
                        atomicAdd(&red[r][1], w * msg);
                    }
                }
            }
            __syncthreads();

            if (tid < 8) {
                int i = i0 + tid;
                float znew = red[tid][1] / red[tid][0];
                store_f_llc(&out[(eb * NC + i) * NT + NP * (s + 1) + ep],
                            resl + 0.5f * znew);           // ALPHA = 0.5
            }
        }
        if (s < STEPS - 1) grid_barrier(bar);
    }
}

extern "C" void kernel_launch(void* const* d_in, const int* in_sizes, int n_in,
                              void* d_out, int out_size, void* d_ws, size_t ws_size,
                              hipStream_t stream)
{
    const float* x    = (const float*)d_in[0];
    const float* g0   = (const float*)d_in[1];
    const float* b0   = (const float*)d_in[2];
    const float* g1   = (const float*)d_in[3];
    const float* b1   = (const float*)d_in[4];
    const float* g2   = (const float*)d_in[5];
    const float* b2   = (const float*)d_in[6];
    const float* Wagg = (const float*)d_in[7];
    const float* bagg = (const float*)d_in[8];
    const float* W1   = (const float*)d_in[9];
    const float* bm1  = (const float*)d_in[10];
    const float* W2   = (const float*)d_in[11];
    // d_in[12] = bm2: uniform shift of e -> invariant under top-k & softmax
    const float* wmsg = (const float*)d_in[13];
    const float* bmsg = (const float*)d_in[14];
    float* out = (float*)d_out;

    float* xn     = (float*)d_ws;                          // 73728 floats
    float* t_ws   = xn + (NB * CT);                        // 9216 floats
    float* res_ws = t_ws + (NB * NP * NC);                 // 9216 floats
    unsigned* bar = (unsigned*)(res_ws + NB * NC * NP);    // 34 words

    hipMemsetAsync(bar, 0, 256, stream);   // zero barrier flags (capturable)
    fused_kernel<<<NBLK, NTHR, 0, stream>>>(x, g0, b0, g1, b1, g2, b2, Wagg,
                                            bagg, W1, bm1, W2, wmsg, bmsg,
                                            out, xn, t_ws, res_ws, bar);
}